// Round 11
// baseline (398.184 us; speedup 1.0000x reference)
//
#include <hip/hip_runtime.h>
#include <hip/hip_bf16.h>
#include <hip/hip_cooperative_groups.h>
#include <math.h>

namespace cg = cooperative_groups;

// (B,Cin,H,W)=(8,128,64,64), Cout=256, K=3, stride=1, pad=1, dil=1
#define B_    8
#define CIN   128
#define Hx    64
#define Wx    64
#define COUT  256
#define HW    4096
#define KTOT  1152      // CIN*9
#define NOFF  18
#define M_    32768     // B*HW
#define OFFSEG (B_ * NOFF * HW)   // 589824 floats per cin-segment partial
#define NCH   36        // K-chunks (chunk = 32 k)

typedef short bf16x8 __attribute__((ext_vector_type(8)));
typedef float f32x4  __attribute__((ext_vector_type(4)));
typedef unsigned short us8 __attribute__((ext_vector_type(8)));

typedef __attribute__((address_space(1))) const unsigned int gu32;
typedef __attribute__((address_space(3))) unsigned int lu32;
static __device__ __forceinline__ void async_cp16(const short* g, short* l) {
  __builtin_amdgcn_global_load_lds((gu32*)g, (lu32*)l, 16, 0, 0);
}

static __device__ __forceinline__ short f2bf(float f) {
  __hip_bfloat16 h = __float2bfloat16(f);
  return *reinterpret_cast<short*>(&h);
}

static __device__ __forceinline__ float b2f(unsigned short u) {
  unsigned int v = ((unsigned int)u) << 16;
  return __uint_as_float(v);
}

// ---------------- K1': offset conv (proven) + wt_cvt merged ----------------
__global__ __launch_bounds__(256, 4) void pre_kernel(
    const float* __restrict__ x, const float* __restrict__ ow,
    const float* __restrict__ ob, float* __restrict__ offp,
    const float* __restrict__ dw, short* __restrict__ Wb) {
  __shared__ __align__(16) float lds_w[16 * 9 * 12];   // [ci][ch][12 (9 taps + pad)]
  int blk = blockIdx.x;
  int tid = threadIdx.x;
  if (blk >= 1024) {
    int t = (blk - 1024) * 256 + tid;       // 294912
    int ki = t & 31;
    int cout = (t >> 5) & 255;
    int kc = t >> 13;                       // 0..35
    int k = kc * 32 + ki;
    int kk = k >> 7, cin = k & 127;
    Wb[t] = f2bf(dw[(cout * CIN + cin) * 9 + kk]);
    return;
  }
  int r = blk & 63, seg = (blk >> 6) & 7, chalf = blk >> 9;
  for (int i = tid; i < 16 * 9 * 12; i += 256) {
    int t = i % 12;
    int rem = i / 12;                       // ci*9 + ch
    int ch = rem % 9, ci = rem / 9;
    lds_w[i] = (t < 9) ? ow[(chalf * 9 + ch) * KTOT + (seg * 16 + ci) * 9 + t] : 0.f;
  }
  __syncthreads();

  int v = r * 256 + tid;                    // 0..16383
  int wp = v & 31, ho = (v >> 5) & 63, b = v >> 11;
  int wo0 = wp * 2;
  float acc0[9], acc1[9];
#pragma unroll
  for (int c = 0; c < 9; ++c) { acc0[c] = 0.f; acc1[c] = 0.f; }
  const float* xb = x + (b * CIN + seg * 16) * HW;
  for (int ci = 0; ci < 16; ++ci) {
    const float* xp = xb + ci * HW;
    float win[3][4];
#pragma unroll
    for (int ky = 0; ky < 3; ++ky) {
      int iy = ho - 1 + ky;
      bool rok = (iy >= 0) & (iy < Hx);
      const float* rowp = xp + iy * Wx;
#pragma unroll
      for (int c = 0; c < 4; ++c) {
        int ix = wo0 - 1 + c;
        win[ky][c] = (rok & (ix >= 0) & (ix < Wx)) ? rowp[ix] : 0.f;
      }
    }
    const float4* wq = (const float4*)&lds_w[ci * 108];
#pragma unroll
    for (int ch = 0; ch < 9; ++ch) {
      float4 w0 = wq[ch * 3 + 0];
      float4 w1 = wq[ch * 3 + 1];
      float4 w2 = wq[ch * 3 + 2];
      float a0 = acc0[ch], a1 = acc1[ch];
      a0 = fmaf(win[0][0], w0.x, a0); a1 = fmaf(win[0][1], w0.x, a1);
      a0 = fmaf(win[0][1], w0.y, a0); a1 = fmaf(win[0][2], w0.y, a1);
      a0 = fmaf(win[0][2], w0.z, a0); a1 = fmaf(win[0][3], w0.z, a1);
      a0 = fmaf(win[1][0], w0.w, a0); a1 = fmaf(win[1][1], w0.w, a1);
      a0 = fmaf(win[1][1], w1.x, a0); a1 = fmaf(win[1][2], w1.x, a1);
      a0 = fmaf(win[1][2], w1.y, a0); a1 = fmaf(win[1][3], w1.y, a1);
      a0 = fmaf(win[2][0], w1.z, a0); a1 = fmaf(win[2][1], w1.z, a1);
      a0 = fmaf(win[2][1], w1.w, a0); a1 = fmaf(win[2][2], w1.w, a1);
      a0 = fmaf(win[2][2], w2.x, a0); a1 = fmaf(win[2][3], w2.x, a1);
      acc0[ch] = a0; acc1[ch] = a1;
    }
  }
  float* op = offp + seg * OFFSEG + (b * NOFF + chalf * 9) * HW + ho * 64 + wo0;
#pragma unroll
  for (int c = 0; c < 9; ++c) {
    float bias = (seg == 0) ? ob[chalf * 9 + c] : 0.f;
    op[c * HW]     = acc0[c] + bias;
    op[c * HW + 1] = acc1[c] + bias;
  }
}

// ---------------- K3: bilinear coefficient tables (proven, 8 partials) ----------------
__global__ __launch_bounds__(256) void coeff_kernel(
    const float* __restrict__ offp, short4* __restrict__ cidx, float4* __restrict__ cwt) {
  int t = blockIdx.x * 256 + threadIdx.x;   // 9*32768
  int m = t & (M_ - 1);
  int kk = t >> 15;                         // 0..8
  int b = m >> 12, ho = (m >> 6) & 63, wo = m & 63;
  int base = (b * NOFF + 2 * kk) * HW + (m & 4095);
  int base2 = base + HW;
  float dy = 0.f, dx = 0.f;
#pragma unroll
  for (int s = 0; s < 8; ++s) {
    dy += offp[base + s * OFFSEG];
    dx += offp[base2 + s * OFFSEG];
  }
  float sy = (float)(ho - 1 + kk / 3) + dy;
  float sx = (float)(wo - 1 + kk % 3) + dx;
  float fy = floorf(sy), fx = floorf(sx);
  int y0 = (int)fy, x0 = (int)fx;
  float wy = sy - fy, wx = sx - fx;
  int y1 = y0 + 1, x1 = x0 + 1;
  int cy0 = min(max(y0, 0), Hx - 1), cy1 = min(max(y1, 0), Hx - 1);
  int cx0 = min(max(x0, 0), Wx - 1), cx1 = min(max(x1, 0), Wx - 1);
  bool vy0 = (y0 >= 0) & (y0 < Hx), vy1 = (y1 >= 0) & (y1 < Hx);
  bool vx0 = (x0 >= 0) & (x0 < Wx), vx1 = (x1 >= 0) & (x1 < Wx);
  short4 id;
  id.x = (short)(cy0 * Wx + cx0); id.y = (short)(cy0 * Wx + cx1);
  id.z = (short)(cy1 * Wx + cx0); id.w = (short)(cy1 * Wx + cx1);
  float4 wv;
  wv.x = (vy0 && vx0) ? (1.f - wy) * (1.f - wx) : 0.f;
  wv.y = (vy0 && vx1) ? (1.f - wy) * wx : 0.f;
  wv.z = (vy1 && vx0) ? wy * (1.f - wx) : 0.f;
  wv.w = (vy1 && vx1) ? wy * wx : 0.f;
  cidx[t] = id;
  cwt[t] = wv;
}

// ---------------- K4: sampler v9 (proven, unchanged) — 8-cin planes, b128 gathers ----------------
__global__ __launch_bounds__(256) void sampler_kernel(
    const float* __restrict__ x, const short4* __restrict__ cidx,
    const float4* __restrict__ cwt, short* __restrict__ Pb) {
  __shared__ __align__(16) us8 ldsp[HW];    // 65536 B: [pixel]{8 bf16 cins}
  int blk = blockIdx.x;                     // 0..511
  int b = blk & 7;
  int g8 = (blk >> 3) & 15;                 // cin-octet 0..15
  int posq = blk >> 7;                      // position quarter 0..3
  int cinq = g8 >> 2;                       // chunk quarter 0..3
  int e8 = g8 & 3;                          // octet slot within chunk (4 octets)
  int tid = threadIdx.x;

  const float* p0 = x + (b * CIN + g8 * 8) * HW;
#pragma unroll
  for (int it = 0; it < 16; ++it) {
    int p = it * 256 + tid;
    us8 pk;
#pragma unroll
    for (int c = 0; c < 8; ++c)
      pk[c] = (unsigned short)f2bf(p0[c * HW + p]);
    ldsp[p] = pk;
  }
  __syncthreads();

  const int pbase = b * HW + posq * 1024 + tid;
  for (int kk = 0; kk < 9; ++kk) {
    int kcg = kk * 4 + cinq;                // 0..35
    const short4* cp = cidx + kk * M_ + pbase;
    const float4* wp = cwt + kk * M_ + pbase;
    short* pb = Pb + (kcg * M_ + pbase) * 32 + e8 * 8;
#pragma unroll
    for (int it = 0; it < 4; ++it) {
      short4 id = cp[it * 256];
      float4 wv = wp[it * 256];
      us8 A  = ldsp[(int)id.x];
      us8 Bv = ldsp[(int)id.y];
      us8 C  = ldsp[(int)id.z];
      us8 D  = ldsp[(int)id.w];
      union { short s[8]; int4 v; } bu;
#pragma unroll
      for (int c = 0; c < 8; ++c) {
        float s = wv.x * b2f(A[c]) + wv.y * b2f(Bv[c])
                + wv.z * b2f(C[c]) + wv.w * b2f(D[c]);
        bu.s[c] = f2bf(s);
      }
      *(int4*)&pb[it * 256 * 32] = bu.v;
    }
  }
}

// ---------------- K5'': cooperative GEMM + BN stats + BN apply + SiLU ----------------
// v11: y was written (33.5MB), re-read + re-written by bn_silu (67MB) -> all
// folded into one cooperative kernel. Phase 1 = proven K-loop + v10's partial
// (sum,sum^2) epilogue; grid.sync; phase 2 = blocks 0..255 reduce one channel
// each -> mean/invstd; grid.sync; phase 3 = stage sc/bt in LDS, silu(v*sc+bt)
// on acc IN REGISTERS, single y write. Grid 512 @ 2 blocks/CU = exactly
// co-resident on 256 CUs (32KB LDS, <=128 VGPR enforced by launch_bounds).
__global__ __launch_bounds__(256, 2) void gemm_bn_kernel(
    const short* __restrict__ Wb, const short* __restrict__ Pb,
    float* __restrict__ y, float* __restrict__ psum, float* __restrict__ psq,
    const float* __restrict__ gamma, const float* __restrict__ beta,
    float* __restrict__ mean, float* __restrict__ invstd) {
  __shared__ __align__(16) short lds[2][8192];   // [buf][ A 4096 | B 4096 ] shorts

  int tid = threadIdx.x;
  int mt = blockIdx.x & 255;
  int ct = blockIdx.x >> 8;
  int cout0 = ct * 128;
  int m0 = mt * 128;

  int lane = tid & 63, wave = tid >> 6;
  int quad = lane >> 4, l16 = lane & 15;
  int wm = (wave & 1) << 6;          // cout sub-tile 0/64
  int wnm = (wave >> 1) << 6;        // m sub-tile 0/64

  int isB = wave >> 1;
  int sub = wave & 1;
  const short* srcbase = isB ? (Pb + m0 * 32) : (Wb + cout0 * 32);
  const int sstride = isB ? (M_ * 32) : (256 * 32);
  const int soff = sub * 2048 + lane * 8;        // shorts
  const int doff = isB * 4096 + sub * 2048 + lane * 8;

  f32x4 zero = {0.f, 0.f, 0.f, 0.f};
  f32x4 acc[4][4];
#pragma unroll
  for (int i = 0; i < 4; ++i)
#pragma unroll
    for (int j = 0; j < 4; ++j) acc[i][j] = zero;

  // prologue: chunk 0 -> buf 0
  {
    const short* s = srcbase + soff;
    short* d = &lds[0][doff];
#pragma unroll
    for (int j = 0; j < 4; ++j)
      async_cp16(s + j * 512, d + j * 512);
  }

  for (int ch = 0; ch < NCH; ++ch) {
    int p = ch & 1;
    __syncthreads();                 // drains DMA -> buf p ready; frag reads of p^1 done
    if (ch < NCH - 1) {
      const short* s = srcbase + (ch + 1) * sstride + soff;
      short* d = &lds[p ^ 1][doff];
#pragma unroll
      for (int j = 0; j < 4; ++j)
        async_cp16(s + j * 512, d + j * 512);   // flies across the MFMAs below
    }
    const short* sa = &lds[p][0];
    const short* sb = &lds[p][4096];
    bf16x8 af[4], bfr[4];
#pragma unroll
    for (int i = 0; i < 4; ++i)
      af[i] = *(const bf16x8*)&sa[(wm + i * 16 + l16) * 32 + quad * 8];
#pragma unroll
    for (int j = 0; j < 4; ++j)
      bfr[j] = *(const bf16x8*)&sb[(wnm + j * 16 + l16) * 32 + quad * 8];
#pragma unroll
    for (int i = 0; i < 4; ++i)
#pragma unroll
      for (int j = 0; j < 4; ++j)
        acc[i][j] = __builtin_amdgcn_mfma_f32_16x16x32_bf16(af[i], bfr[j], acc[i][j], 0, 0, 0);
  }

  // phase 1 epilogue: per-channel (sum, sum^2) partials (v10-proven reduction)
  __syncthreads();                   // all lds frag reads done; reuse as scratch
  float* redsum = (float*)&lds[0][0];          // [2][128]
  float* redsq  = redsum + 256;
#pragma unroll
  for (int i = 0; i < 4; ++i) {
#pragma unroll
    for (int r2 = 0; r2 < 4; ++r2) {
      float s = 0.f, q = 0.f;
#pragma unroll
      for (int j = 0; j < 4; ++j) {
        float v = acc[i][j][r2];
        s += v;
        q = fmaf(v, v, q);
      }
#pragma unroll
      for (int o = 8; o > 0; o >>= 1) {
        s += __shfl_down(s, o);
        q += __shfl_down(q, o);
      }
      if (l16 == 0) {
        int cl = wm + i * 16 + quad * 4 + r2;    // 0..127
        int half = wave >> 1;
        redsum[half * 128 + cl] = s;
        redsq [half * 128 + cl] = q;
      }
    }
  }
  __syncthreads();
  if (tid < 128) {
    float s = redsum[tid] + redsum[128 + tid];
    float q = redsq [tid] + redsq [128 + tid];
    psum[(cout0 + tid) * 256 + mt] = s;
    psq [(cout0 + tid) * 256 + mt] = q;
  }

  cg::grid_group grid = cg::this_grid();
  __threadfence();
  grid.sync();

  // phase 2: blocks 0..255 finalize one channel each
  if (blockIdx.x < 256) {
    int c = blockIdx.x;
    float s = psum[c * 256 + tid];
    float q = psq [c * 256 + tid];
#pragma unroll
    for (int o = 32; o > 0; o >>= 1) {
      s += __shfl_down(s, o);
      q += __shfl_down(q, o);
    }
    float* rs = (float*)&lds[0][0];
    float* rq = rs + 4;
    int wid = tid >> 6, ln = tid & 63;
    if (ln == 0) { rs[wid] = s; rq[wid] = q; }
    __syncthreads();
    if (tid == 0) {
      float S = rs[0] + rs[1] + rs[2] + rs[3];
      float Q = rq[0] + rq[1] + rq[2] + rq[3];
      float m = S / 32768.f;
      mean[c] = m;
      invstd[c] = rsqrtf(Q / 32768.f - m * m + 1e-5f);
    }
  }
  __threadfence();
  grid.sync();

  // phase 3: stage sc/bt, apply BN+SiLU to acc in regs, single y write
  float* scb = (float*)&lds[0][0];   // [128]
  float* btb = scb + 128;
  __syncthreads();
  if (tid < 128) {
    int c = cout0 + tid;
    float m = mean[c];
    float sc = invstd[c] * gamma[c];
    scb[tid] = sc;
    btb[tid] = fmaf(-m, sc, beta[c]);
  }
  __syncthreads();
#pragma unroll
  for (int i = 0; i < 4; ++i) {
    int crow = cout0 + wm + i * 16 + quad * 4;
#pragma unroll
    for (int j = 0; j < 4; ++j) {
      int m = m0 + wnm + j * 16 + l16;
      int b = m >> 12;
      float* yp = y + (b * COUT + crow) * HW + (m & 4095);
#pragma unroll
      for (int r2 = 0; r2 < 4; ++r2) {
        int cl = wm + i * 16 + quad * 4 + r2;
        float t = fmaf(acc[i][j][r2], scb[cl], btb[cl]);
        yp[r2 * HW] = t / (1.f + expf(-t));
      }
    }
  }
}

extern "C" void kernel_launch(void* const* d_in, const int* in_sizes, int n_in,
                              void* d_out, int out_size, void* d_ws, size_t ws_size,
                              hipStream_t stream) {
  const float* x     = (const float*)d_in[0];
  const float* ow    = (const float*)d_in[1];
  const float* ob    = (const float*)d_in[2];
  const float* dw    = (const float*)d_in[3];
  // d_in[4] = dconv bias: cancelled exactly by BN mean-subtraction
  const float* gamma = (const float*)d_in[5];
  const float* beta  = (const float*)d_in[6];
  float* y = (float*)d_out;                  // final output, written ONCE

  // ws layout (float offsets), total 25,641,472 floats = 102.5 MB (ws = 256 MiB)
  float*  ws   = (float*)d_ws;
  short*  Pb   = (short*)ws;                 // 36*32768*32 shorts = 18874368 floats
  float*  offp = ws + 18874368;              // 8 * 589824 = 4718592
  short4* cidx = (short4*)(ws + 23592960);   // 9*32768 short4 = 589824 floats
  float4* cwt  = (float4*)(ws + 24182784);   // 9*32768 float4 = 1179648 floats
  short*  Wb   = (short*)(ws + 25362432);    // 294912 shorts = 147456 floats
  float*  mean   = ws + 25509888;            // 256
  float*  invstd = ws + 25510144;            // 256
  float*  psum   = ws + 25510400;            // 256*256 = 65536
  float*  psq    = ws + 25575936;            // 65536

  pre_kernel<<<2176, 256, 0, stream>>>(x, ow, ob, offp, dw, Wb);
  coeff_kernel<<<1152, 256, 0, stream>>>(offp, cidx, cwt);
  sampler_kernel<<<512, 256, 0, stream>>>(x, cidx, cwt, Pb);

  void* kargs[] = {(void*)&Wb, (void*)&Pb, (void*)&y, (void*)&psum, (void*)&psq,
                   (void*)&gamma, (void*)&beta, (void*)&mean, (void*)&invstd};
  hipLaunchCooperativeKernel((const void*)gemm_bn_kernel, dim3(512), dim3(256),
                             kargs, 0, stream);
}

// Round 12
// 190.064 us; speedup vs baseline: 2.0950x; 2.0950x over previous
//
#include <hip/hip_runtime.h>
#include <hip/hip_bf16.h>
#include <math.h>

// (B,Cin,H,W)=(8,128,64,64), Cout=256, K=3, stride=1, pad=1, dil=1
#define B_    8
#define CIN   128
#define Hx    64
#define Wx    64
#define COUT  256
#define HW    4096
#define KTOT  1152      // CIN*9
#define NOFF  18
#define M_    32768     // B*HW
#define OFFSEG (B_ * NOFF * HW)   // 589824 floats per cin-segment partial
#define NCH   36        // K-chunks (chunk = 32 k)

typedef short bf16x8 __attribute__((ext_vector_type(8)));
typedef float f32x4  __attribute__((ext_vector_type(4)));
typedef unsigned short us8 __attribute__((ext_vector_type(8)));

typedef __attribute__((address_space(1))) const unsigned int gu32;
typedef __attribute__((address_space(3))) unsigned int lu32;
static __device__ __forceinline__ void async_cp16(const short* g, short* l) {
  __builtin_amdgcn_global_load_lds((gu32*)g, (lu32*)l, 16, 0, 0);
}

static __device__ __forceinline__ short f2bf(float f) {
  __hip_bfloat16 h = __float2bfloat16(f);
  return *reinterpret_cast<short*>(&h);
}

static __device__ __forceinline__ float b2f(unsigned short u) {
  unsigned int v = ((unsigned int)u) << 16;
  return __uint_as_float(v);
}

// ---------------- K1': offset conv (proven) + wt_cvt merged ----------------
__global__ __launch_bounds__(256, 4) void pre_kernel(
    const float* __restrict__ x, const float* __restrict__ ow,
    const float* __restrict__ ob, float* __restrict__ offp,
    const float* __restrict__ dw, short* __restrict__ Wb) {
  __shared__ __align__(16) float lds_w[16 * 9 * 12];   // [ci][ch][12 (9 taps + pad)]
  int blk = blockIdx.x;
  int tid = threadIdx.x;
  if (blk >= 1024) {
    int t = (blk - 1024) * 256 + tid;       // 294912
    int ki = t & 31;
    int cout = (t >> 5) & 255;
    int kc = t >> 13;                       // 0..35
    int k = kc * 32 + ki;
    int kk = k >> 7, cin = k & 127;
    Wb[t] = f2bf(dw[(cout * CIN + cin) * 9 + kk]);
    return;
  }
  int r = blk & 63, seg = (blk >> 6) & 7, chalf = blk >> 9;
  for (int i = tid; i < 16 * 9 * 12; i += 256) {
    int t = i % 12;
    int rem = i / 12;                       // ci*9 + ch
    int ch = rem % 9, ci = rem / 9;
    lds_w[i] = (t < 9) ? ow[(chalf * 9 + ch) * KTOT + (seg * 16 + ci) * 9 + t] : 0.f;
  }
  __syncthreads();

  int v = r * 256 + tid;                    // 0..16383
  int wp = v & 31, ho = (v >> 5) & 63, b = v >> 11;
  int wo0 = wp * 2;
  float acc0[9], acc1[9];
#pragma unroll
  for (int c = 0; c < 9; ++c) { acc0[c] = 0.f; acc1[c] = 0.f; }
  const float* xb = x + (b * CIN + seg * 16) * HW;
  for (int ci = 0; ci < 16; ++ci) {
    const float* xp = xb + ci * HW;
    float win[3][4];
#pragma unroll
    for (int ky = 0; ky < 3; ++ky) {
      int iy = ho - 1 + ky;
      bool rok = (iy >= 0) & (iy < Hx);
      const float* rowp = xp + iy * Wx;
#pragma unroll
      for (int c = 0; c < 4; ++c) {
        int ix = wo0 - 1 + c;
        win[ky][c] = (rok & (ix >= 0) & (ix < Wx)) ? rowp[ix] : 0.f;
      }
    }
    const float4* wq = (const float4*)&lds_w[ci * 108];
#pragma unroll
    for (int ch = 0; ch < 9; ++ch) {
      float4 w0 = wq[ch * 3 + 0];
      float4 w1 = wq[ch * 3 + 1];
      float4 w2 = wq[ch * 3 + 2];
      float a0 = acc0[ch], a1 = acc1[ch];
      a0 = fmaf(win[0][0], w0.x, a0); a1 = fmaf(win[0][1], w0.x, a1);
      a0 = fmaf(win[0][1], w0.y, a0); a1 = fmaf(win[0][2], w0.y, a1);
      a0 = fmaf(win[0][2], w0.z, a0); a1 = fmaf(win[0][3], w0.z, a1);
      a0 = fmaf(win[1][0], w0.w, a0); a1 = fmaf(win[1][1], w0.w, a1);
      a0 = fmaf(win[1][1], w1.x, a0); a1 = fmaf(win[1][2], w1.x, a1);
      a0 = fmaf(win[1][2], w1.y, a0); a1 = fmaf(win[1][3], w1.y, a1);
      a0 = fmaf(win[2][0], w1.z, a0); a1 = fmaf(win[2][1], w1.z, a1);
      a0 = fmaf(win[2][1], w1.w, a0); a1 = fmaf(win[2][2], w1.w, a1);
      a0 = fmaf(win[2][2], w2.x, a0); a1 = fmaf(win[2][3], w2.x, a1);
      acc0[ch] = a0; acc1[ch] = a1;
    }
  }
  float* op = offp + seg * OFFSEG + (b * NOFF + chalf * 9) * HW + ho * 64 + wo0;
#pragma unroll
  for (int c = 0; c < 9; ++c) {
    float bias = (seg == 0) ? ob[chalf * 9 + c] : 0.f;
    op[c * HW]     = acc0[c] + bias;
    op[c * HW + 1] = acc1[c] + bias;
  }
}

// ---------------- K3: bilinear coefficient tables (proven, 8 partials) ----------------
__global__ __launch_bounds__(256) void coeff_kernel(
    const float* __restrict__ offp, short4* __restrict__ cidx, float4* __restrict__ cwt) {
  int t = blockIdx.x * 256 + threadIdx.x;   // 9*32768
  int m = t & (M_ - 1);
  int kk = t >> 15;                         // 0..8
  int b = m >> 12, ho = (m >> 6) & 63, wo = m & 63;
  int base = (b * NOFF + 2 * kk) * HW + (m & 4095);
  int base2 = base + HW;
  float dy = 0.f, dx = 0.f;
#pragma unroll
  for (int s = 0; s < 8; ++s) {
    dy += offp[base + s * OFFSEG];
    dx += offp[base2 + s * OFFSEG];
  }
  float sy = (float)(ho - 1 + kk / 3) + dy;
  float sx = (float)(wo - 1 + kk % 3) + dx;
  float fy = floorf(sy), fx = floorf(sx);
  int y0 = (int)fy, x0 = (int)fx;
  float wy = sy - fy, wx = sx - fx;
  int y1 = y0 + 1, x1 = x0 + 1;
  int cy0 = min(max(y0, 0), Hx - 1), cy1 = min(max(y1, 0), Hx - 1);
  int cx0 = min(max(x0, 0), Wx - 1), cx1 = min(max(x1, 0), Wx - 1);
  bool vy0 = (y0 >= 0) & (y0 < Hx), vy1 = (y1 >= 0) & (y1 < Hx);
  bool vx0 = (x0 >= 0) & (x0 < Wx), vx1 = (x1 >= 0) & (x1 < Wx);
  short4 id;
  id.x = (short)(cy0 * Wx + cx0); id.y = (short)(cy0 * Wx + cx1);
  id.z = (short)(cy1 * Wx + cx0); id.w = (short)(cy1 * Wx + cx1);
  float4 wv;
  wv.x = (vy0 && vx0) ? (1.f - wy) * (1.f - wx) : 0.f;
  wv.y = (vy0 && vx1) ? (1.f - wy) * wx : 0.f;
  wv.z = (vy1 && vx0) ? wy * (1.f - wx) : 0.f;
  wv.w = (vy1 && vx1) ? wy * wx : 0.f;
  cidx[t] = id;
  cwt[t] = wv;
}

// ---------------- K4: sampler v9 (proven, unchanged) — 8-cin planes, b128 gathers ----------------
__global__ __launch_bounds__(256) void sampler_kernel(
    const float* __restrict__ x, const short4* __restrict__ cidx,
    const float4* __restrict__ cwt, short* __restrict__ Pb) {
  __shared__ __align__(16) us8 ldsp[HW];    // 65536 B: [pixel]{8 bf16 cins}
  int blk = blockIdx.x;                     // 0..511
  int b = blk & 7;
  int g8 = (blk >> 3) & 15;                 // cin-octet 0..15
  int posq = blk >> 7;                      // position quarter 0..3
  int cinq = g8 >> 2;                       // chunk quarter 0..3
  int e8 = g8 & 3;                          // octet slot within chunk (4 octets)
  int tid = threadIdx.x;

  const float* p0 = x + (b * CIN + g8 * 8) * HW;
#pragma unroll
  for (int it = 0; it < 16; ++it) {
    int p = it * 256 + tid;
    us8 pk;
#pragma unroll
    for (int c = 0; c < 8; ++c)
      pk[c] = (unsigned short)f2bf(p0[c * HW + p]);
    ldsp[p] = pk;
  }
  __syncthreads();

  const int pbase = b * HW + posq * 1024 + tid;
  for (int kk = 0; kk < 9; ++kk) {
    int kcg = kk * 4 + cinq;                // 0..35
    const short4* cp = cidx + kk * M_ + pbase;
    const float4* wp = cwt + kk * M_ + pbase;
    short* pb = Pb + (kcg * M_ + pbase) * 32 + e8 * 8;
#pragma unroll
    for (int it = 0; it < 4; ++it) {
      short4 id = cp[it * 256];
      float4 wv = wp[it * 256];
      us8 A  = ldsp[(int)id.x];
      us8 Bv = ldsp[(int)id.y];
      us8 C  = ldsp[(int)id.z];
      us8 D  = ldsp[(int)id.w];
      union { short s[8]; int4 v; } bu;
#pragma unroll
      for (int c = 0; c < 8; ++c) {
        float s = wv.x * b2f(A[c]) + wv.y * b2f(Bv[c])
                + wv.z * b2f(C[c]) + wv.w * b2f(D[c]);
        bu.s[c] = f2bf(s);
      }
      *(int4*)&pb[it * 256 * 32] = bu.v;
    }
  }
}

// ---------------- K5: bf16 MFMA GEMM v12 — 128cout x 64m tile, 4 blocks/CU ----------------
// Post-mortem v11 (coop fusion, 228us all-idle): cooperative grid.sync cost
// unexplained and catastrophic -> axis closed, reverted to v10 chain. v12
// attacks gemm's exposed per-chunk vmcnt(0)+barrier drain (the m97-structure
// stall) with TLP, the one mechanism m114 says works: halve the m-tile ->
// grid 1024, LDS 24KB/block (dbuf of A 8KB + B 4KB), launch_bounds(256,4)
// -> 4 blocks/CU = 16 waves/CU (was 8). acc 4x2 (32 AGPR), well under the
// 128-reg cap. Pb traffic unchanged; blocks i, i+512 share an XCD
// (512%8==0) for ct-pair L2 reuse. Epilogue: y write + (sum,sum^2)
// partials -> psum/psq[c][512].
__global__ __launch_bounds__(256, 4) void gemm_kernel(
    const short* __restrict__ Wb, const short* __restrict__ Pb,
    float* __restrict__ y, float* __restrict__ psum, float* __restrict__ psq) {
  __shared__ __align__(16) short lds[2][6144];   // [buf][ A 4096 | B 2048 ] shorts

  int tid = threadIdx.x;
  int mt = blockIdx.x & 511;
  int ct = blockIdx.x >> 9;
  int cout0 = ct * 128;
  int m0 = mt * 64;

  int lane = tid & 63, wave = tid >> 6;
  int quad = lane >> 4, l16 = lane & 15;
  int wm = (wave & 1) << 6;          // cout sub-tile 0/64
  int wnm = (wave >> 1) << 5;        // m sub-tile 0/32

  // staging roles: waves 0,1 -> A halves (2048 shorts each);
  //                waves 2,3 -> B halves (1024 shorts each)
  int isB = wave >> 1;
  int sub = wave & 1;
  const short* srcbase = isB ? (Pb + m0 * 32) : (Wb + cout0 * 32);
  const int sstride = isB ? (M_ * 32) : (256 * 32);
  const int soff = isB ? (sub * 1024 + lane * 8) : (sub * 2048 + lane * 8);
  const int doff = isB ? (4096 + sub * 1024 + lane * 8) : (sub * 2048 + lane * 8);
  const int ncp = isB ? 2 : 4;       // cp16 rounds (x512 shorts)

  f32x4 zero = {0.f, 0.f, 0.f, 0.f};
  f32x4 acc[4][2];
#pragma unroll
  for (int i = 0; i < 4; ++i)
#pragma unroll
    for (int j = 0; j < 2; ++j) acc[i][j] = zero;

  // prologue: chunk 0 -> buf 0
  {
    const short* s = srcbase + soff;
    short* d = &lds[0][doff];
    for (int j = 0; j < ncp; ++j)
      async_cp16(s + j * 512, d + j * 512);
  }

  for (int ch = 0; ch < NCH; ++ch) {
    int p = ch & 1;
    __syncthreads();                 // drains DMA -> buf p ready; frag reads of p^1 done
    if (ch < NCH - 1) {
      const short* s = srcbase + (ch + 1) * sstride + soff;
      short* d = &lds[p ^ 1][doff];
      for (int j = 0; j < ncp; ++j)
        async_cp16(s + j * 512, d + j * 512);   // flies across the MFMAs below
    }
    const short* sa = &lds[p][0];
    const short* sb = &lds[p][4096];
    bf16x8 af[4], bfr[2];
#pragma unroll
    for (int i = 0; i < 4; ++i)
      af[i] = *(const bf16x8*)&sa[(wm + i * 16 + l16) * 32 + quad * 8];
#pragma unroll
    for (int j = 0; j < 2; ++j)
      bfr[j] = *(const bf16x8*)&sb[(wnm + j * 16 + l16) * 32 + quad * 8];
#pragma unroll
    for (int i = 0; i < 4; ++i)
#pragma unroll
      for (int j = 0; j < 2; ++j)
        acc[i][j] = __builtin_amdgcn_mfma_f32_16x16x32_bf16(af[i], bfr[j], acc[i][j], 0, 0, 0);
  }

  // epilogue 1: write y once (dconv bias cancels in BN mean-subtraction)
#pragma unroll
  for (int i = 0; i < 4; ++i) {
    int crow = cout0 + wm + i * 16 + quad * 4;
#pragma unroll
    for (int j = 0; j < 2; ++j) {
      int m = m0 + wnm + j * 16 + l16;
      int b = m >> 12;
      float* yp = y + (b * COUT + crow) * HW + (m & 4095);
#pragma unroll
      for (int r2 = 0; r2 < 4; ++r2)
        yp[r2 * HW] = acc[i][j][r2];
    }
  }

  // epilogue 2: per-channel (sum, sum^2) partials over this block's 64 m.
  __syncthreads();                   // all lds frag reads done; reuse as scratch
  float* redsum = (float*)&lds[0][0];          // [2][128]
  float* redsq  = redsum + 256;
#pragma unroll
  for (int i = 0; i < 4; ++i) {
#pragma unroll
    for (int r2 = 0; r2 < 4; ++r2) {
      float s = 0.f, q = 0.f;
#pragma unroll
      for (int j = 0; j < 2; ++j) {
        float v = acc[i][j][r2];
        s += v;
        q = fmaf(v, v, q);
      }
#pragma unroll
      for (int o = 8; o > 0; o >>= 1) {
        s += __shfl_down(s, o);
        q += __shfl_down(q, o);
      }
      if (l16 == 0) {
        int cl = wm + i * 16 + quad * 4 + r2;    // 0..127
        int half = wave >> 1;
        redsum[half * 128 + cl] = s;
        redsq [half * 128 + cl] = q;
      }
    }
  }
  __syncthreads();
  if (tid < 128) {
    float s = redsum[tid] + redsum[128 + tid];
    float q = redsq [tid] + redsq [128 + tid];
    psum[(cout0 + tid) * 512 + mt] = s;
    psq [(cout0 + tid) * 512 + mt] = q;
  }
}

// ---------------- K6': BN finalize from 1MB partials (512-wide) ----------------
__global__ __launch_bounds__(256) void bn_finalize_kernel(
    const float* __restrict__ psum, const float* __restrict__ psq,
    float* __restrict__ mean, float* __restrict__ invstd) {
  int c = blockIdx.x;
  int tid = threadIdx.x;
  float s = psum[c * 512 + tid] + psum[c * 512 + 256 + tid];
  float q = psq [c * 512 + tid] + psq [c * 512 + 256 + tid];
#pragma unroll
  for (int o = 32; o > 0; o >>= 1) {
    s += __shfl_down(s, o);
    q += __shfl_down(q, o);
  }
  __shared__ float rs[4], rq[4];
  int wid = tid >> 6, ln = tid & 63;
  if (ln == 0) { rs[wid] = s; rq[wid] = q; }
  __syncthreads();
  if (tid == 0) {
    float S = rs[0] + rs[1] + rs[2] + rs[3];
    float Q = rq[0] + rq[1] + rq[2] + rq[3];
    float m = S / 32768.f;
    mean[c] = m;
    invstd[c] = rsqrtf(Q / 32768.f - m * m + 1e-5f);
  }
}

// ---------------- K7: BN apply + SiLU, in place on y (= d_out) (proven) ----------------
__global__ __launch_bounds__(256) void bn_silu_kernel(
    float* __restrict__ y, const float* __restrict__ mean,
    const float* __restrict__ invstd, const float* __restrict__ gamma,
    const float* __restrict__ beta) {
  int i4 = blockIdx.x * 256 + threadIdx.x;   // 2097152 float4s
  int c = (i4 >> 10) & 255;
  float4 v = ((const float4*)y)[i4];
  float m = mean[c], sc = invstd[c] * gamma[c], bt = beta[c];
  float t0 = (v.x - m) * sc + bt;
  float t1 = (v.y - m) * sc + bt;
  float t2 = (v.z - m) * sc + bt;
  float t3 = (v.w - m) * sc + bt;
  float4 o;
  o.x = t0 / (1.f + expf(-t0));
  o.y = t1 / (1.f + expf(-t1));
  o.z = t2 / (1.f + expf(-t2));
  o.w = t3 / (1.f + expf(-t3));
  ((float4*)y)[i4] = o;
}

extern "C" void kernel_launch(void* const* d_in, const int* in_sizes, int n_in,
                              void* d_out, int out_size, void* d_ws, size_t ws_size,
                              hipStream_t stream) {
  const float* x     = (const float*)d_in[0];
  const float* ow    = (const float*)d_in[1];
  const float* ob    = (const float*)d_in[2];
  const float* dw    = (const float*)d_in[3];
  // d_in[4] = dconv bias: cancelled exactly by BN mean-subtraction
  const float* gamma = (const float*)d_in[5];
  const float* beta  = (const float*)d_in[6];
  float* y = (float*)d_out;                  // y buffer, finished in place

  // ws layout (float offsets), total 25,772,544 floats = 103.1 MB (ws = 256 MiB)
  float*  ws   = (float*)d_ws;
  short*  Pb   = (short*)ws;                 // 36*32768*32 shorts = 18874368 floats
  float*  offp = ws + 18874368;              // 8 * 589824 = 4718592
  short4* cidx = (short4*)(ws + 23592960);   // 9*32768 short4 = 589824 floats
  float4* cwt  = (float4*)(ws + 24182784);   // 9*32768 float4 = 1179648 floats
  short*  Wb   = (short*)(ws + 25362432);    // 294912 shorts = 147456 floats
  float*  mean   = ws + 25509888;            // 256
  float*  invstd = ws + 25510144;            // 256
  float*  psum   = ws + 25510400;            // 256*512 = 131072
  float*  psq    = ws + 25641472;            // 131072

  pre_kernel<<<2176, 256, 0, stream>>>(x, ow, ob, offp, dw, Wb);
  coeff_kernel<<<1152, 256, 0, stream>>>(offp, cidx, cwt);
  sampler_kernel<<<512, 256, 0, stream>>>(x, cidx, cwt, Pb);
  gemm_kernel<<<1024, 256, 0, stream>>>(Wb, Pb, y, psum, psq);
  bn_finalize_kernel<<<256, 256, 0, stream>>>(psum, psq, mean, invstd);
  bn_silu_kernel<<<8192, 256, 0, stream>>>(y, mean, invstd, gamma, beta);
}

// Round 13
// 182.428 us; speedup vs baseline: 2.1827x; 1.0419x over previous
//
#include <hip/hip_runtime.h>
#include <hip/hip_bf16.h>
#include <math.h>

// (B,Cin,H,W)=(8,128,64,64), Cout=256, K=3, stride=1, pad=1, dil=1
#define B_    8
#define CIN   128
#define Hx    64
#define Wx    64
#define COUT  256
#define HW    4096
#define KTOT  1152      // CIN*9
#define NOFF  18
#define M_    32768     // B*HW
#define OFFSEG (B_ * NOFF * HW)   // 589824 floats per cin-segment partial
#define NCH   36        // K-chunks (chunk = 32 k)

typedef short bf16x8 __attribute__((ext_vector_type(8)));
typedef float f32x4  __attribute__((ext_vector_type(4)));
typedef unsigned short us8 __attribute__((ext_vector_type(8)));

typedef __attribute__((address_space(1))) const unsigned int gu32;
typedef __attribute__((address_space(3))) unsigned int lu32;
static __device__ __forceinline__ void async_cp16(const short* g, short* l) {
  __builtin_amdgcn_global_load_lds((gu32*)g, (lu32*)l, 16, 0, 0);
}

static __device__ __forceinline__ short f2bf(float f) {
  __hip_bfloat16 h = __float2bfloat16(f);
  return *reinterpret_cast<short*>(&h);
}

static __device__ __forceinline__ float b2f(unsigned short u) {
  unsigned int v = ((unsigned int)u) << 16;
  return __uint_as_float(v);
}

// ---------------- K1': offset conv (proven) + wt_cvt merged ----------------
__global__ __launch_bounds__(256, 4) void pre_kernel(
    const float* __restrict__ x, const float* __restrict__ ow,
    const float* __restrict__ ob, float* __restrict__ offp,
    const float* __restrict__ dw, short* __restrict__ Wb) {
  __shared__ __align__(16) float lds_w[16 * 9 * 12];   // [ci][ch][12 (9 taps + pad)]
  int blk = blockIdx.x;
  int tid = threadIdx.x;
  if (blk >= 1024) {
    int t = (blk - 1024) * 256 + tid;       // 294912
    int ki = t & 31;
    int cout = (t >> 5) & 255;
    int kc = t >> 13;                       // 0..35
    int k = kc * 32 + ki;
    int kk = k >> 7, cin = k & 127;
    Wb[t] = f2bf(dw[(cout * CIN + cin) * 9 + kk]);
    return;
  }
  int r = blk & 63, seg = (blk >> 6) & 7, chalf = blk >> 9;
  for (int i = tid; i < 16 * 9 * 12; i += 256) {
    int t = i % 12;
    int rem = i / 12;                       // ci*9 + ch
    int ch = rem % 9, ci = rem / 9;
    lds_w[i] = (t < 9) ? ow[(chalf * 9 + ch) * KTOT + (seg * 16 + ci) * 9 + t] : 0.f;
  }
  __syncthreads();

  int v = r * 256 + tid;                    // 0..16383
  int wp = v & 31, ho = (v >> 5) & 63, b = v >> 11;
  int wo0 = wp * 2;
  float acc0[9], acc1[9];
#pragma unroll
  for (int c = 0; c < 9; ++c) { acc0[c] = 0.f; acc1[c] = 0.f; }
  const float* xb = x + (b * CIN + seg * 16) * HW;
  for (int ci = 0; ci < 16; ++ci) {
    const float* xp = xb + ci * HW;
    float win[3][4];
#pragma unroll
    for (int ky = 0; ky < 3; ++ky) {
      int iy = ho - 1 + ky;
      bool rok = (iy >= 0) & (iy < Hx);
      const float* rowp = xp + iy * Wx;
#pragma unroll
      for (int c = 0; c < 4; ++c) {
        int ix = wo0 - 1 + c;
        win[ky][c] = (rok & (ix >= 0) & (ix < Wx)) ? rowp[ix] : 0.f;
      }
    }
    const float4* wq = (const float4*)&lds_w[ci * 108];
#pragma unroll
    for (int ch = 0; ch < 9; ++ch) {
      float4 w0 = wq[ch * 3 + 0];
      float4 w1 = wq[ch * 3 + 1];
      float4 w2 = wq[ch * 3 + 2];
      float a0 = acc0[ch], a1 = acc1[ch];
      a0 = fmaf(win[0][0], w0.x, a0); a1 = fmaf(win[0][1], w0.x, a1);
      a0 = fmaf(win[0][1], w0.y, a0); a1 = fmaf(win[0][2], w0.y, a1);
      a0 = fmaf(win[0][2], w0.z, a0); a1 = fmaf(win[0][3], w0.z, a1);
      a0 = fmaf(win[1][0], w0.w, a0); a1 = fmaf(win[1][1], w0.w, a1);
      a0 = fmaf(win[1][1], w1.x, a0); a1 = fmaf(win[1][2], w1.x, a1);
      a0 = fmaf(win[1][2], w1.y, a0); a1 = fmaf(win[1][3], w1.y, a1);
      a0 = fmaf(win[2][0], w1.z, a0); a1 = fmaf(win[2][1], w1.z, a1);
      a0 = fmaf(win[2][1], w1.w, a0); a1 = fmaf(win[2][2], w1.w, a1);
      a0 = fmaf(win[2][2], w2.x, a0); a1 = fmaf(win[2][3], w2.x, a1);
      acc0[ch] = a0; acc1[ch] = a1;
    }
  }
  float* op = offp + seg * OFFSEG + (b * NOFF + chalf * 9) * HW + ho * 64 + wo0;
#pragma unroll
  for (int c = 0; c < 9; ++c) {
    float bias = (seg == 0) ? ob[chalf * 9 + c] : 0.f;
    op[c * HW]     = acc0[c] + bias;
    op[c * HW + 1] = acc1[c] + bias;
  }
}

// ---------------- K3: bilinear coefficient tables (proven, 8 partials) ----------------
__global__ __launch_bounds__(256) void coeff_kernel(
    const float* __restrict__ offp, short4* __restrict__ cidx, float4* __restrict__ cwt) {
  int t = blockIdx.x * 256 + threadIdx.x;   // 9*32768
  int m = t & (M_ - 1);
  int kk = t >> 15;                         // 0..8
  int b = m >> 12, ho = (m >> 6) & 63, wo = m & 63;
  int base = (b * NOFF + 2 * kk) * HW + (m & 4095);
  int base2 = base + HW;
  float dy = 0.f, dx = 0.f;
#pragma unroll
  for (int s = 0; s < 8; ++s) {
    dy += offp[base + s * OFFSEG];
    dx += offp[base2 + s * OFFSEG];
  }
  float sy = (float)(ho - 1 + kk / 3) + dy;
  float sx = (float)(wo - 1 + kk % 3) + dx;
  float fy = floorf(sy), fx = floorf(sx);
  int y0 = (int)fy, x0 = (int)fx;
  float wy = sy - fy, wx = sx - fx;
  int y1 = y0 + 1, x1 = x0 + 1;
  int cy0 = min(max(y0, 0), Hx - 1), cy1 = min(max(y1, 0), Hx - 1);
  int cx0 = min(max(x0, 0), Wx - 1), cx1 = min(max(x1, 0), Wx - 1);
  bool vy0 = (y0 >= 0) & (y0 < Hx), vy1 = (y1 >= 0) & (y1 < Hx);
  bool vx0 = (x0 >= 0) & (x0 < Wx), vx1 = (x1 >= 0) & (x1 < Wx);
  short4 id;
  id.x = (short)(cy0 * Wx + cx0); id.y = (short)(cy0 * Wx + cx1);
  id.z = (short)(cy1 * Wx + cx0); id.w = (short)(cy1 * Wx + cx1);
  float4 wv;
  wv.x = (vy0 && vx0) ? (1.f - wy) * (1.f - wx) : 0.f;
  wv.y = (vy0 && vx1) ? (1.f - wy) * wx : 0.f;
  wv.z = (vy1 && vx0) ? wy * (1.f - wx) : 0.f;
  wv.w = (vy1 && vx1) ? wy * wx : 0.f;
  cidx[t] = id;
  cwt[t] = wv;
}

// ---------------- K4: sampler v9 (proven, unchanged) — 8-cin planes, b128 gathers ----------------
__global__ __launch_bounds__(256) void sampler_kernel(
    const float* __restrict__ x, const short4* __restrict__ cidx,
    const float4* __restrict__ cwt, short* __restrict__ Pb) {
  __shared__ __align__(16) us8 ldsp[HW];    // 65536 B: [pixel]{8 bf16 cins}
  int blk = blockIdx.x;                     // 0..511
  int b = blk & 7;
  int g8 = (blk >> 3) & 15;                 // cin-octet 0..15
  int posq = blk >> 7;                      // position quarter 0..3
  int cinq = g8 >> 2;                       // chunk quarter 0..3
  int e8 = g8 & 3;                          // octet slot within chunk (4 octets)
  int tid = threadIdx.x;

  const float* p0 = x + (b * CIN + g8 * 8) * HW;
#pragma unroll
  for (int it = 0; it < 16; ++it) {
    int p = it * 256 + tid;
    us8 pk;
#pragma unroll
    for (int c = 0; c < 8; ++c)
      pk[c] = (unsigned short)f2bf(p0[c * HW + p]);
    ldsp[p] = pk;
  }
  __syncthreads();

  const int pbase = b * HW + posq * 1024 + tid;
  for (int kk = 0; kk < 9; ++kk) {
    int kcg = kk * 4 + cinq;                // 0..35
    const short4* cp = cidx + kk * M_ + pbase;
    const float4* wp = cwt + kk * M_ + pbase;
    short* pb = Pb + (kcg * M_ + pbase) * 32 + e8 * 8;
#pragma unroll
    for (int it = 0; it < 4; ++it) {
      short4 id = cp[it * 256];
      float4 wv = wp[it * 256];
      us8 A  = ldsp[(int)id.x];
      us8 Bv = ldsp[(int)id.y];
      us8 C  = ldsp[(int)id.z];
      us8 D  = ldsp[(int)id.w];
      union { short s[8]; int4 v; } bu;
#pragma unroll
      for (int c = 0; c < 8; ++c) {
        float s = wv.x * b2f(A[c]) + wv.y * b2f(Bv[c])
                + wv.z * b2f(C[c]) + wv.w * b2f(D[c]);
        bu.s[c] = f2bf(s);
      }
      *(int4*)&pb[it * 256 * 32] = bu.v;
    }
  }
}

// ---------------- K5: bf16 MFMA GEMM (v10-proven 128x128) + BN partial stats ----------------
// v13: v12's 128x64 tile regressed (190 vs 182.6) -> reverted to the proven
// 128x128 / 2 blocks/CU shape. Epilogue writes y + per-channel (sum,sum^2)
// partials (exclusive psum/psq[c][mt] slots, no atomics).
__global__ __launch_bounds__(256, 2) void gemm_kernel(
    const short* __restrict__ Wb, const short* __restrict__ Pb,
    float* __restrict__ y, float* __restrict__ psum, float* __restrict__ psq) {
  __shared__ __align__(16) short lds[2][8192];   // [buf][ A 4096 | B 4096 ] shorts

  int tid = threadIdx.x;
  int mt = blockIdx.x & 255;
  int ct = blockIdx.x >> 8;
  int cout0 = ct * 128;
  int m0 = mt * 128;

  int lane = tid & 63, wave = tid >> 6;
  int quad = lane >> 4, l16 = lane & 15;
  int wm = (wave & 1) << 6;          // cout sub-tile 0/64
  int wnm = (wave >> 1) << 6;        // m sub-tile 0/64

  int isB = wave >> 1;
  int sub = wave & 1;
  const short* srcbase = isB ? (Pb + m0 * 32) : (Wb + cout0 * 32);
  const int sstride = isB ? (M_ * 32) : (256 * 32);
  const int soff = sub * 2048 + lane * 8;        // shorts
  const int doff = isB * 4096 + sub * 2048 + lane * 8;

  f32x4 zero = {0.f, 0.f, 0.f, 0.f};
  f32x4 acc[4][4];
#pragma unroll
  for (int i = 0; i < 4; ++i)
#pragma unroll
    for (int j = 0; j < 4; ++j) acc[i][j] = zero;

  // prologue: chunk 0 -> buf 0
  {
    const short* s = srcbase + soff;
    short* d = &lds[0][doff];
#pragma unroll
    for (int j = 0; j < 4; ++j)
      async_cp16(s + j * 512, d + j * 512);
  }

  for (int ch = 0; ch < NCH; ++ch) {
    int p = ch & 1;
    __syncthreads();                 // drains DMA -> buf p ready; frag reads of p^1 done
    if (ch < NCH - 1) {
      const short* s = srcbase + (ch + 1) * sstride + soff;
      short* d = &lds[p ^ 1][doff];
#pragma unroll
      for (int j = 0; j < 4; ++j)
        async_cp16(s + j * 512, d + j * 512);   // flies across the MFMAs below
    }
    const short* sa = &lds[p][0];
    const short* sb = &lds[p][4096];
    bf16x8 af[4], bfr[4];
#pragma unroll
    for (int i = 0; i < 4; ++i)
      af[i] = *(const bf16x8*)&sa[(wm + i * 16 + l16) * 32 + quad * 8];
#pragma unroll
    for (int j = 0; j < 4; ++j)
      bfr[j] = *(const bf16x8*)&sb[(wnm + j * 16 + l16) * 32 + quad * 8];
#pragma unroll
    for (int i = 0; i < 4; ++i)
#pragma unroll
      for (int j = 0; j < 4; ++j)
        acc[i][j] = __builtin_amdgcn_mfma_f32_16x16x32_bf16(af[i], bfr[j], acc[i][j], 0, 0, 0);
  }

  // epilogue 1: write y once (dconv bias cancels in BN mean-subtraction)
#pragma unroll
  for (int i = 0; i < 4; ++i) {
    int crow = cout0 + wm + i * 16 + quad * 4;
#pragma unroll
    for (int j = 0; j < 4; ++j) {
      int m = m0 + wnm + j * 16 + l16;
      int b = m >> 12;
      float* yp = y + (b * COUT + crow) * HW + (m & 4095);
#pragma unroll
      for (int r2 = 0; r2 < 4; ++r2)
        yp[r2 * HW] = acc[i][j][r2];
    }
  }

  // epilogue 2: per-channel (sum, sum^2) partials over this block's 128 m.
  __syncthreads();                   // all lds frag reads done; reuse as scratch
  float* redsum = (float*)&lds[0][0];          // [2][128]
  float* redsq  = redsum + 256;
#pragma unroll
  for (int i = 0; i < 4; ++i) {
#pragma unroll
    for (int r2 = 0; r2 < 4; ++r2) {
      float s = 0.f, q = 0.f;
#pragma unroll
      for (int j = 0; j < 4; ++j) {
        float v = acc[i][j][r2];
        s += v;
        q = fmaf(v, v, q);
      }
#pragma unroll
      for (int o = 8; o > 0; o >>= 1) {
        s += __shfl_down(s, o);
        q += __shfl_down(q, o);
      }
      if (l16 == 0) {
        int cl = wm + i * 16 + quad * 4 + r2;    // 0..127
        int half = wave >> 1;
        redsum[half * 128 + cl] = s;
        redsq [half * 128 + cl] = q;
      }
    }
  }
  __syncthreads();
  if (tid < 128) {
    float s = redsum[tid] + redsum[128 + tid];
    float q = redsq [tid] + redsq [128 + tid];
    psum[(cout0 + tid) * 256 + mt] = s;
    psq [(cout0 + tid) * 256 + mt] = q;
  }
}

// ---------------- K7': BN stats (from partials, in-block) + apply + SiLU ----------------
// v13: bn_finalize folded in. Each block's channel c = (blk>>2)&255 is
// block-uniform (256 float4s span 1024 floats, exactly within one channel
// segment). Threads reduce psum/psq[c][0..255] (1 elem/thread, L2-hot;
// same summation order as the old bn_finalize -> bit-identical stats),
// then apply BN+SiLU in place.
__global__ __launch_bounds__(256) void bn_silu_kernel(
    float* __restrict__ y, const float* __restrict__ psum,
    const float* __restrict__ psq, const float* __restrict__ gamma,
    const float* __restrict__ beta) {
  int blk = blockIdx.x;                      // 0..8191
  int tid = threadIdx.x;
  int c = (blk >> 2) & 255;

  float s = psum[c * 256 + tid];
  float q = psq [c * 256 + tid];
#pragma unroll
  for (int o = 32; o > 0; o >>= 1) {
    s += __shfl_down(s, o);
    q += __shfl_down(q, o);
  }
  __shared__ float rs[4], rq[4], sb[2];
  int wid = tid >> 6, ln = tid & 63;
  if (ln == 0) { rs[wid] = s; rq[wid] = q; }
  __syncthreads();
  if (tid == 0) {
    float S = rs[0] + rs[1] + rs[2] + rs[3];
    float Q = rq[0] + rq[1] + rq[2] + rq[3];
    float m = S / 32768.f;
    float is = rsqrtf(Q / 32768.f - m * m + 1e-5f);
    float sc = is * gamma[c];
    sb[0] = sc;
    sb[1] = fmaf(-m, sc, beta[c]);
  }
  __syncthreads();
  float sc = sb[0], bt = sb[1];

  int i4 = blk * 256 + tid;                  // 2097152 float4s
  float4 v = ((const float4*)y)[i4];
  float t0 = fmaf(v.x, sc, bt);
  float t1 = fmaf(v.y, sc, bt);
  float t2 = fmaf(v.z, sc, bt);
  float t3 = fmaf(v.w, sc, bt);
  float4 o;
  o.x = t0 / (1.f + expf(-t0));
  o.y = t1 / (1.f + expf(-t1));
  o.z = t2 / (1.f + expf(-t2));
  o.w = t3 / (1.f + expf(-t3));
  ((float4*)y)[i4] = o;
}

extern "C" void kernel_launch(void* const* d_in, const int* in_sizes, int n_in,
                              void* d_out, int out_size, void* d_ws, size_t ws_size,
                              hipStream_t stream) {
  const float* x     = (const float*)d_in[0];
  const float* ow    = (const float*)d_in[1];
  const float* ob    = (const float*)d_in[2];
  const float* dw    = (const float*)d_in[3];
  // d_in[4] = dconv bias: cancelled exactly by BN mean-subtraction
  const float* gamma = (const float*)d_in[5];
  const float* beta  = (const float*)d_in[6];
  float* y = (float*)d_out;                  // y buffer, finished in place

  // ws layout (float offsets), total 25,641,472 floats = 102.5 MB (ws = 256 MiB)
  float*  ws   = (float*)d_ws;
  short*  Pb   = (short*)ws;                 // 36*32768*32 shorts = 18874368 floats
  float*  offp = ws + 18874368;              // 8 * 589824 = 4718592
  short4* cidx = (short4*)(ws + 23592960);   // 9*32768 short4 = 589824 floats
  float4* cwt  = (float4*)(ws + 24182784);   // 9*32768 float4 = 1179648 floats
  short*  Wb   = (short*)(ws + 25362432);    // 294912 shorts = 147456 floats
  float*  psum   = ws + 25510400;            // 256*256 = 65536
  float*  psq    = ws + 25575936;            // 65536

  pre_kernel<<<2176, 256, 0, stream>>>(x, ow, ob, offp, dw, Wb);
  coeff_kernel<<<1152, 256, 0, stream>>>(offp, cidx, cwt);
  sampler_kernel<<<512, 256, 0, stream>>>(x, cidx, cwt, Pb);
  gemm_kernel<<<512, 256, 0, stream>>>(Wb, Pb, y, psum, psq);
  bn_silu_kernel<<<8192, 256, 0, stream>>>(y, psum, psq, gamma, beta);
}